// Round 3
// baseline (1772.103 us; speedup 1.0000x reference)
//
#include <hip/hip_runtime.h>
#include <math.h>

// HungarianLoss: B=128 samples, each a 192x192 LSAP on
// cost[q][j] = -softmax(pred[q])[tgt[j]], then mean CE with matched classes.
//
// One block per sample. 4 waves fill the cost matrix (LDS); wave 0 then runs
// a lapjv-style solver: column reduction + 2-pass augmenting row reduction
// (near-optimal duals, most rows assigned), then exact Dijkstra shortest
// augmenting path (reference algorithm) for the few remaining free rows.
// All solver state in registers, distributed 3 rows/cols per lane;
// uniform gathers via v_readlane, wave reduces via DPP.

#define BB 128
#define QQ 192
#define CC 512
#define NBIG 1e30f

template<int CTRL>
__device__ __forceinline__ int dpp_mov(int x) {
    return __builtin_amdgcn_update_dpp(x, x, CTRL, 0xf, 0xf, false);
}

// 64-lane reduces; result valid in lane 63 (validated exact in R1/R2).
__device__ __forceinline__ float wave_min64(float x) {
    x = fminf(x, __int_as_float(dpp_mov<0x111>(__float_as_int(x))));
    x = fminf(x, __int_as_float(dpp_mov<0x112>(__float_as_int(x))));
    x = fminf(x, __int_as_float(dpp_mov<0x114>(__float_as_int(x))));
    x = fminf(x, __int_as_float(dpp_mov<0x118>(__float_as_int(x))));
    x = fminf(x, __int_as_float(dpp_mov<0x142>(__float_as_int(x))));
    x = fminf(x, __int_as_float(dpp_mov<0x143>(__float_as_int(x))));
    return __int_as_float(__builtin_amdgcn_readlane(__float_as_int(x), 63));
}
__device__ __forceinline__ float wave_max64(float x) {
    x = fmaxf(x, __int_as_float(dpp_mov<0x111>(__float_as_int(x))));
    x = fmaxf(x, __int_as_float(dpp_mov<0x112>(__float_as_int(x))));
    x = fmaxf(x, __int_as_float(dpp_mov<0x114>(__float_as_int(x))));
    x = fmaxf(x, __int_as_float(dpp_mov<0x118>(__float_as_int(x))));
    x = fmaxf(x, __int_as_float(dpp_mov<0x142>(__float_as_int(x))));
    x = fmaxf(x, __int_as_float(dpp_mov<0x143>(__float_as_int(x))));
    return __int_as_float(__builtin_amdgcn_readlane(__float_as_int(x), 63));
}
__device__ __forceinline__ float wave_sum64(float x) {
    x += __int_as_float(dpp_mov<0x111>(__float_as_int(x)));
    x += __int_as_float(dpp_mov<0x112>(__float_as_int(x)));
    x += __int_as_float(dpp_mov<0x114>(__float_as_int(x)));
    x += __int_as_float(dpp_mov<0x118>(__float_as_int(x)));
    x += __int_as_float(dpp_mov<0x142>(__float_as_int(x)));
    x += __int_as_float(dpp_mov<0x143>(__float_as_int(x)));
    return __int_as_float(__builtin_amdgcn_readlane(__float_as_int(x), 63));
}
// (min, second-min counting duplicates) over 64 lanes; same dataflow as sum
// (non-overlapping partition into lane 63), so multiset semantics are exact.
__device__ __forceinline__ void wave_minsub64(float& mn, float& sb) {
#define MS_STEP(CTRL) { \
    float omn = __int_as_float(dpp_mov<CTRL>(__float_as_int(mn))); \
    float osb = __int_as_float(dpp_mov<CTRL>(__float_as_int(sb))); \
    float nmn = fminf(mn, omn); \
    sb = fminf(fminf(sb, osb), fmaxf(mn, omn)); \
    mn = nmn; }
    MS_STEP(0x111) MS_STEP(0x112) MS_STEP(0x114) MS_STEP(0x118)
    MS_STEP(0x142) MS_STEP(0x143)
#undef MS_STEP
    mn = __int_as_float(__builtin_amdgcn_readlane(__float_as_int(mn), 63));
    sb = __int_as_float(__builtin_amdgcn_readlane(__float_as_int(sb), 63));
}

__device__ __forceinline__ float readlane_f(float v, int l) {
    return __int_as_float(__builtin_amdgcn_readlane(__float_as_int(v), l));
}
__device__ __forceinline__ int readlane_i(int v, int l) {
    return __builtin_amdgcn_readlane(v, l);
}

// distributed-register accessors (row/col idx -> owner lane = idx&63, slot = idx>>6)
#define GET_I3(a, idx) readlane_i((((idx)>>6)==0) ? a##0 : ((((idx)>>6)==1) ? a##1 : a##2), (idx)&63)
#define GET_F3(a, idx) readlane_f((((idx)>>6)==0) ? a##0 : ((((idx)>>6)==1) ? a##1 : a##2), (idx)&63)
#define SET_I3(a, idx, val) do { const int _s=(idx)>>6, _l=(idx)&63; \
    if (_s==0) { if (lane==_l) a##0=(val); } \
    else if (_s==1) { if (lane==_l) a##1=(val); } \
    else { if (lane==_l) a##2=(val); } } while(0)
#define SUB_F3(a, idx, val) do { const int _s=(idx)>>6, _l=(idx)&63; \
    if (_s==0) { if (lane==_l) a##0-=(val); } \
    else if (_s==1) { if (lane==_l) a##1-=(val); } \
    else { if (lane==_l) a##2-=(val); } } while(0)

__launch_bounds__(256)
__global__ void hungarian_kernel(const float* __restrict__ pred,
                                 const int* __restrict__ targets,
                                 float* __restrict__ ws_part) {
    const int b = blockIdx.x;
    const int lane = threadIdx.x & 63;
    const int wv = threadIdx.x >> 6;

    extern __shared__ float smem[];
    float* cost     = smem;                    // [QQ*QQ] read-only after fill
    float* spc_lds  = cost + QQ * QQ;          // [QQ] scratch (v dump / spc dump)
    float* lse_lds  = spc_lds + QQ;            // [QQ]
    int*   tgt_lds  = (int*)(lse_lds + QQ);    // [QQ]
    int*   free_lds = tgt_lds + QQ;            // [QQ] free-row list

    // ---- targets (each wave loads; wave0 also mirrors to LDS) ----
    const int t0 = targets[b * QQ + lane];
    const int t1 = targets[b * QQ + lane + 64];
    const int t2 = targets[b * QQ + lane + 128];
    if (wv == 0) { tgt_lds[lane] = t0; tgt_lds[lane + 64] = t1; tgt_lds[lane + 128] = t2; }

    // ---- fill: 4 waves, 48 rows each ----
    const float* predb = pred + (size_t)b * QQ * CC;
    {
        const int q0 = wv * 48, q1 = q0 + 48;
        float x[8];
        #pragma unroll
        for (int k = 0; k < 8; k++) x[k] = predb[(size_t)q0 * CC + lane + 64 * k];
        for (int q = q0; q < q1; q++) {
            const float* row = predb + (size_t)q * CC;
            float g0 = row[t0], g1 = row[t1], g2 = row[t2];
            float xn[8];
            if (q + 1 < q1) {
                const float* nrow = row + CC;
                #pragma unroll
                for (int k = 0; k < 8; k++) xn[k] = nrow[lane + 64 * k];
            }
            float mx = x[0];
            #pragma unroll
            for (int k = 1; k < 8; k++) mx = fmaxf(mx, x[k]);
            mx = wave_max64(mx);
            float s = 0.f;
            #pragma unroll
            for (int k = 0; k < 8; k++) s += expf(x[k] - mx);
            s = wave_sum64(s);
            float lse = mx + logf(s);
            if (lane == 0) lse_lds[q] = lse;
            cost[q * QQ + lane]       = -expf(g0 - lse);
            cost[q * QQ + lane + 64]  = -expf(g1 - lse);
            cost[q * QQ + lane + 128] = -expf(g2 - lse);
            #pragma unroll
            for (int k = 0; k < 8; k++) x[k] = xn[k];
        }
    }
    __syncthreads();
    if (wv != 0) return;
    // single wave from here on: in-wave LDS ordering via waitcnt, no barriers.

    // ---- solver state: 3 rows + 3 cols per lane ----
    float u0 = 0.f, u1 = 0.f, u2 = 0.f;   // row duals
    float v0, v1, v2;                     // col duals
    int   c0 = -1, c1 = -1, c2 = -1;      // col4row
    int   r0 = -1, r1 = -1, r2 = -1;      // row4col

    // ---- phase 1: column reduction (v[j] = col min, greedy assign desc j) ----
    float cv0 = NBIG, cv1 = NBIG, cv2 = NBIG;
    int   ci0 = 0, ci1 = 0, ci2 = 0;
    for (int i = 0; i < QQ; i++) {
        const float* crow = cost + i * QQ;
        float a = crow[lane], e = crow[lane + 64], f = crow[lane + 128];
        if (a < cv0) { cv0 = a; ci0 = i; }
        if (e < cv1) { cv1 = e; ci1 = i; }
        if (f < cv2) { cv2 = f; ci2 = i; }
    }
    v0 = cv0; v1 = cv1; v2 = cv2;
    for (int j = QQ - 1; j >= 0; j--) {
        const int imin = GET_I3(ci, j);
        const int xi = GET_I3(c, imin);
        if (xi < 0) {
            SET_I3(c, imin, j);
            SET_I3(r, j, imin);
        }
    }

    // ---- build free-row list (ascending) ----
    int numfree;
    {
        unsigned long long m0 = __ballot(c0 < 0), m1 = __ballot(c1 < 0), m2 = __ballot(c2 < 0);
        const int n0 = __popcll(m0), n1 = __popcll(m1);
        const unsigned long long below = (1ull << lane) - 1ull;
        if (c0 < 0) free_lds[__popcll(m0 & below)] = lane;
        if (c1 < 0) free_lds[n0 + __popcll(m1 & below)] = lane + 64;
        if (c2 < 0) free_lds[n0 + n1 + __popcll(m2 & below)] = lane + 128;
        numfree = n0 + n1 + __popcll(m2);
    }

    // ---- phase 2: augmenting row reduction, 2 passes (lapjv) ----
    int guard = 0;
    for (int pass = 0; pass < 2; pass++) {
        int k = 0;
        const int prv = numfree;
        numfree = 0;
        while (k < prv && guard < 3000) {
            guard++;
            const int i = free_lds[k]; k++;
            const float* crow = cost + i * QQ;
            const float h0 = crow[lane] - v0;
            const float h1 = crow[lane + 64] - v1;
            const float h2 = crow[lane + 128] - v2;
            // per-lane (min, submin)
            float lo = fminf(h0, h1), hi = fmaxf(h0, h1);
            float mn = fminf(lo, h2);
            float sb = fminf(hi, fmaxf(lo, h2));
            wave_minsub64(mn, sb);
            // j1 = first col achieving mn (global order = slot-major = ascending j)
            unsigned long long B0 = __ballot(h0 == mn);
            unsigned long long B1 = __ballot(h1 == mn);
            unsigned long long B2 = __ballot(h2 == mn);
            int j1;
            if (B0) j1 = __ffsll(B0) - 1;
            else if (B1) j1 = 64 + __ffsll(B1) - 1;
            else j1 = 128 + __ffsll(B2) - 1;
            int i0 = GET_I3(r, j1);
            if (mn < sb) {
                SUB_F3(v, j1, sb - mn);
            } else if (i0 >= 0) {
                // duplicate minimum: take the second occurrence
                if (j1 < 64) B0 &= (B0 - 1);
                else if (j1 < 128) B1 &= (B1 - 1);
                else B2 &= (B2 - 1);
                int j2;
                if (B0 | B1 | B2) {
                    if (B0) j2 = __ffsll(B0) - 1;
                    else if (B1) j2 = 64 + __ffsll(B1) - 1;
                    else j2 = 128 + __ffsll(B2) - 1;
                } else {
                    unsigned long long C0 = __ballot(h0 == sb);
                    unsigned long long C1 = __ballot(h1 == sb);
                    unsigned long long C2 = __ballot(h2 == sb);
                    if (C0) j2 = __ffsll(C0) - 1;
                    else if (C1) j2 = 64 + __ffsll(C1) - 1;
                    else j2 = 128 + __ffsll(C2) - 1;
                }
                j1 = j2;
                i0 = GET_I3(r, j1);
            }
            SET_I3(c, i, j1);
            SET_I3(r, j1, i);
            if (i0 >= 0) {
                SET_I3(c, i0, -1);  // keep x/y consistent (lapjv tracks via list only)
                if (mn < sb) {
                    k--;
                    if (lane == 0) free_lds[k] = i0;  // reprocess immediately
                } else {
                    if (lane == 0) free_lds[numfree] = i0;  // process next pass
                    numfree++;
                }
            }
        }
    }

    // ---- duals for Dijkstra phase: u[i] = c[i][x[i]] - v[x[i]] (CS), 0 if free ----
    spc_lds[lane] = v0; spc_lds[lane + 64] = v1; spc_lds[lane + 128] = v2;
    u0 = (c0 >= 0) ? cost[lane * QQ + c0] - spc_lds[c0] : 0.f;
    u1 = (c1 >= 0) ? cost[(lane + 64) * QQ + c1] - spc_lds[c1] : 0.f;
    u2 = (c2 >= 0) ? cost[(lane + 128) * QQ + c2] - spc_lds[c2] : 0.f;

    // ---- phase 3: exact shortest augmenting path for remaining free rows ----
    for (int cur = 0; cur < QQ; cur++) {
        if (GET_I3(c, cur) >= 0) continue;

        float spc0 = NBIG, spc1 = NBIG, spc2 = NBIG;
        int   p0 = 0, p1 = 0, p2 = 0;
        int   sc0 = 0, sc1 = 0, sc2 = 0;
        int   sr0 = 0, sr1 = 0, sr2 = 0;
        int   i = cur;
        float minVal = 0.f;
        int   sink = -1;

        while (sink < 0) {
            sr0 |= (i == lane); sr1 |= (i == lane + 64); sr2 |= (i == lane + 128);
            const float ui = GET_F3(u, i);
            const float* crow = cost + i * QQ;
            {
                float r = ((minVal + crow[lane]) - ui) - v0;
                if (!sc0 && r < spc0) { spc0 = r; p0 = i; }
            }
            {
                float r = ((minVal + crow[lane + 64]) - ui) - v1;
                if (!sc1 && r < spc1) { spc1 = r; p1 = i; }
            }
            {
                float r = ((minVal + crow[lane + 128]) - ui) - v2;
                if (!sc2 && r < spc2) { spc2 = r; p2 = i; }
            }
            const float m0 = sc0 ? NBIG : spc0;
            const float m1 = sc1 ? NBIG : spc1;
            const float m2 = sc2 ? NBIG : spc2;

            minVal = wave_min64(fminf(m0, fminf(m1, m2)));
            unsigned long long b0 = __ballot(m0 == minVal);
            unsigned long long b1 = __ballot(m1 == minVal);
            unsigned long long b2 = __ballot(m2 == minVal);
            int jstar;
            if (b0)      jstar = __ffsll(b0) - 1;
            else if (b1) jstar = 64 + __ffsll(b1) - 1;
            else         jstar = 128 + __ffsll(b2) - 1;

            sc0 |= (jstar == lane); sc1 |= (jstar == lane + 64); sc2 |= (jstar == lane + 128);
            const int rj = GET_I3(r, jstar);
            if (rj < 0) sink = jstar; else i = rj;
        }

        // dual updates
        u0 += (cur == lane) ? minVal : 0.f;
        u1 += (cur == lane + 64) ? minVal : 0.f;
        u2 += (cur == lane + 128) ? minVal : 0.f;
        spc_lds[lane] = spc0; spc_lds[lane + 64] = spc1; spc_lds[lane + 128] = spc2;
        if (sr0 && lane != cur)         u0 += minVal - spc_lds[c0];
        if (sr1 && (lane + 64) != cur)  u1 += minVal - spc_lds[c1];
        if (sr2 && (lane + 128) != cur) u2 += minVal - spc_lds[c2];
        if (sc0) v0 -= (minVal - spc0);
        if (sc1) v1 -= (minVal - spc1);
        if (sc2) v2 -= (minVal - spc2);

        // augment along stored path
        int j = sink;
        while (true) {
            const int pj = GET_I3(p, j);
            SET_I3(r, j, pj);
            const int nj = GET_I3(c, pj);
            SET_I3(c, pj, j);
            if (pj == cur) break;
            j = nj;
        }
    }

    // ---- CE partial: sum_r (lse[r] - pred[r][tgt[col4row[r]]]) ----
    float part = 0.f;
    {
        const int tc0 = tgt_lds[c0], tc1 = tgt_lds[c1], tc2 = tgt_lds[c2];
        part += lse_lds[lane]       - predb[(size_t)lane * CC + tc0];
        part += lse_lds[lane + 64]  - predb[(size_t)(lane + 64) * CC + tc1];
        part += lse_lds[lane + 128] - predb[(size_t)(lane + 128) * CC + tc2];
    }
    part = wave_sum64(part);
    if (lane == 0) ws_part[b] = part;
}

__launch_bounds__(64)
__global__ void reduce_kernel(const float* __restrict__ ws_part,
                              float* __restrict__ out) {
    int lane = threadIdx.x;
    float s = ws_part[lane] + ws_part[lane + 64];
    s = wave_sum64(s);
    if (lane == 0) out[0] = s / (float)(BB * QQ);
}

extern "C" void kernel_launch(void* const* d_in, const int* in_sizes, int n_in,
                              void* d_out, int out_size, void* d_ws, size_t ws_size,
                              hipStream_t stream) {
    const float* pred = (const float*)d_in[0];
    const int* targets = (const int*)d_in[1];
    float* out = (float*)d_out;
    float* ws = (float*)d_ws;

    const int lds_bytes = (QQ * QQ + 4 * QQ) * (int)sizeof(float);  // 150528 B

    hipLaunchKernelGGL(hungarian_kernel, dim3(BB), dim3(256), lds_bytes, stream,
                       pred, targets, ws);
    hipLaunchKernelGGL(reduce_kernel, dim3(1), dim3(64), 0, stream, ws, out);
}

// Round 4
// 1725.325 us; speedup vs baseline: 1.0271x; 1.0271x over previous
//
#include <hip/hip_runtime.h>
#include <math.h>

// HungarianLoss: B=128 samples, each a 192x192 LSAP on
// cost[q][j] = -softmax(pred[q])[tgt[j]], then mean CE with matched classes.
//
// One block per sample. 4 waves fill the cost matrix (LDS); wave 0 then:
//   phase 1: column reduction (v[j] = col min) + greedy assignment
//            -> feasible duals (u=0), ~60-75% rows assigned, NO serial search
//   phase 3: exact Dijkstra shortest augmenting path (reference algorithm)
//            for the remaining free rows, starting from the good duals.
// (R3's lapjv augmenting-row-reduction phase removed: duplicate target
//  classes create exactly-identical cost columns -> min==submin ties ->
//  steal/reprocess thrash, measured as 2x LDS-scan count and +580us.)
// All solver state in registers, distributed 3 rows/cols per lane;
// uniform gathers via v_readlane, wave reduces via DPP.

#define BB 128
#define QQ 192
#define CC 512
#define NBIG 1e30f

template<int CTRL>
__device__ __forceinline__ int dpp_mov(int x) {
    return __builtin_amdgcn_update_dpp(x, x, CTRL, 0xf, 0xf, false);
}

// 64-lane reduces; result uniform via lane 63 (validated exact in R1-R3).
__device__ __forceinline__ float wave_min64(float x) {
    x = fminf(x, __int_as_float(dpp_mov<0x111>(__float_as_int(x))));
    x = fminf(x, __int_as_float(dpp_mov<0x112>(__float_as_int(x))));
    x = fminf(x, __int_as_float(dpp_mov<0x114>(__float_as_int(x))));
    x = fminf(x, __int_as_float(dpp_mov<0x118>(__float_as_int(x))));
    x = fminf(x, __int_as_float(dpp_mov<0x142>(__float_as_int(x))));
    x = fminf(x, __int_as_float(dpp_mov<0x143>(__float_as_int(x))));
    return __int_as_float(__builtin_amdgcn_readlane(__float_as_int(x), 63));
}
__device__ __forceinline__ float wave_max64(float x) {
    x = fmaxf(x, __int_as_float(dpp_mov<0x111>(__float_as_int(x))));
    x = fmaxf(x, __int_as_float(dpp_mov<0x112>(__float_as_int(x))));
    x = fmaxf(x, __int_as_float(dpp_mov<0x114>(__float_as_int(x))));
    x = fmaxf(x, __int_as_float(dpp_mov<0x118>(__float_as_int(x))));
    x = fmaxf(x, __int_as_float(dpp_mov<0x142>(__float_as_int(x))));
    x = fmaxf(x, __int_as_float(dpp_mov<0x143>(__float_as_int(x))));
    return __int_as_float(__builtin_amdgcn_readlane(__float_as_int(x), 63));
}
__device__ __forceinline__ float wave_sum64(float x) {
    x += __int_as_float(dpp_mov<0x111>(__float_as_int(x)));
    x += __int_as_float(dpp_mov<0x112>(__float_as_int(x)));
    x += __int_as_float(dpp_mov<0x114>(__float_as_int(x)));
    x += __int_as_float(dpp_mov<0x118>(__float_as_int(x)));
    x += __int_as_float(dpp_mov<0x142>(__float_as_int(x)));
    x += __int_as_float(dpp_mov<0x143>(__float_as_int(x)));
    return __int_as_float(__builtin_amdgcn_readlane(__float_as_int(x), 63));
}

__device__ __forceinline__ float readlane_f(float v, int l) {
    return __int_as_float(__builtin_amdgcn_readlane(__float_as_int(v), l));
}
__device__ __forceinline__ int readlane_i(int v, int l) {
    return __builtin_amdgcn_readlane(v, l);
}

// distributed-register accessors (row/col idx -> owner lane = idx&63, slot = idx>>6)
#define GET_I3(a, idx) readlane_i((((idx)>>6)==0) ? a##0 : ((((idx)>>6)==1) ? a##1 : a##2), (idx)&63)
#define GET_F3(a, idx) readlane_f((((idx)>>6)==0) ? a##0 : ((((idx)>>6)==1) ? a##1 : a##2), (idx)&63)
#define SET_I3(a, idx, val) do { const int _s=(idx)>>6, _l=(idx)&63; \
    if (_s==0) { if (lane==_l) a##0=(val); } \
    else if (_s==1) { if (lane==_l) a##1=(val); } \
    else { if (lane==_l) a##2=(val); } } while(0)

__launch_bounds__(256)
__global__ void hungarian_kernel(const float* __restrict__ pred,
                                 const int* __restrict__ targets,
                                 float* __restrict__ ws_part) {
    const int b = blockIdx.x;
    const int lane = threadIdx.x & 63;
    const int wv = threadIdx.x >> 6;

    extern __shared__ float smem[];
    float* cost     = smem;                    // [QQ*QQ] read-only after fill
    float* spc_lds  = cost + QQ * QQ;          // [QQ] per-row-solve spc dump
    float* lse_lds  = spc_lds + QQ;            // [QQ]
    int*   tgt_lds  = (int*)(lse_lds + QQ);    // [QQ]
    int*   free_lds = tgt_lds + QQ;            // [QQ] free-row list

    // ---- targets (each wave loads; wave0 also mirrors to LDS) ----
    const int t0 = targets[b * QQ + lane];
    const int t1 = targets[b * QQ + lane + 64];
    const int t2 = targets[b * QQ + lane + 128];
    if (wv == 0) { tgt_lds[lane] = t0; tgt_lds[lane + 64] = t1; tgt_lds[lane + 128] = t2; }

    // ---- fill: 4 waves, 48 rows each ----
    const float* predb = pred + (size_t)b * QQ * CC;
    {
        const int q0 = wv * 48, q1 = q0 + 48;
        float x[8];
        #pragma unroll
        for (int k = 0; k < 8; k++) x[k] = predb[(size_t)q0 * CC + lane + 64 * k];
        for (int q = q0; q < q1; q++) {
            const float* row = predb + (size_t)q * CC;
            float g0 = row[t0], g1 = row[t1], g2 = row[t2];
            float xn[8];
            if (q + 1 < q1) {
                const float* nrow = row + CC;
                #pragma unroll
                for (int k = 0; k < 8; k++) xn[k] = nrow[lane + 64 * k];
            }
            float mx = x[0];
            #pragma unroll
            for (int k = 1; k < 8; k++) mx = fmaxf(mx, x[k]);
            mx = wave_max64(mx);
            float s = 0.f;
            #pragma unroll
            for (int k = 0; k < 8; k++) s += expf(x[k] - mx);
            s = wave_sum64(s);
            float lse = mx + logf(s);
            if (lane == 0) lse_lds[q] = lse;
            cost[q * QQ + lane]       = -expf(g0 - lse);
            cost[q * QQ + lane + 64]  = -expf(g1 - lse);
            cost[q * QQ + lane + 128] = -expf(g2 - lse);
            #pragma unroll
            for (int k = 0; k < 8; k++) x[k] = xn[k];
        }
    }
    __syncthreads();
    if (wv != 0) return;
    // single wave from here on: in-wave LDS ordering via waitcnt, no barriers.

    // ---- solver state: 3 rows + 3 cols per lane ----
    float u0 = 0.f, u1 = 0.f, u2 = 0.f;   // row duals (stay 0 after phase 1:
                                          // assigned pairs have c[i][j]-v[j]=0)
    float v0, v1, v2;                     // col duals
    int   c0 = -1, c1 = -1, c2 = -1;      // col4row
    int   r0 = -1, r1 = -1, r2 = -1;      // row4col

    // ---- phase 1: column reduction (v[j] = col min, greedy assign desc j) ----
    float cv0 = NBIG, cv1 = NBIG, cv2 = NBIG;
    int   ci0 = 0, ci1 = 0, ci2 = 0;
    for (int i = 0; i < QQ; i++) {
        const float* crow = cost + i * QQ;
        float a = crow[lane], e = crow[lane + 64], f = crow[lane + 128];
        if (a < cv0) { cv0 = a; ci0 = i; }
        if (e < cv1) { cv1 = e; ci1 = i; }
        if (f < cv2) { cv2 = f; ci2 = i; }
    }
    v0 = cv0; v1 = cv1; v2 = cv2;
    for (int j = QQ - 1; j >= 0; j--) {
        const int imin = GET_I3(ci, j);
        const int xi = GET_I3(c, imin);
        if (xi < 0) {
            SET_I3(c, imin, j);
            SET_I3(r, j, imin);
        }
    }

    // ---- build free-row list (ascending) ----
    int numfree;
    {
        unsigned long long m0 = __ballot(c0 < 0), m1 = __ballot(c1 < 0), m2 = __ballot(c2 < 0);
        const int n0 = __popcll(m0), n1 = __popcll(m1);
        const unsigned long long below = (1ull << lane) - 1ull;
        if (c0 < 0) free_lds[__popcll(m0 & below)] = lane;
        if (c1 < 0) free_lds[n0 + __popcll(m1 & below)] = lane + 64;
        if (c2 < 0) free_lds[n0 + n1 + __popcll(m2 & below)] = lane + 128;
        numfree = n0 + n1 + __popcll(m2);
    }

    // ---- phase 3: exact shortest augmenting path for each free row ----
    for (int k = 0; k < numfree; k++) {
        const int cur = free_lds[k];

        float spc0 = NBIG, spc1 = NBIG, spc2 = NBIG;
        int   p0 = 0, p1 = 0, p2 = 0;
        int   sc0 = 0, sc1 = 0, sc2 = 0;
        int   sr0 = 0, sr1 = 0, sr2 = 0;
        int   i = cur;
        float minVal = 0.f;
        int   sink = -1;

        while (sink < 0) {
            sr0 |= (i == lane); sr1 |= (i == lane + 64); sr2 |= (i == lane + 128);
            const float ui = GET_F3(u, i);
            const float* crow = cost + i * QQ;
            {
                float r = ((minVal + crow[lane]) - ui) - v0;
                if (!sc0 && r < spc0) { spc0 = r; p0 = i; }
            }
            {
                float r = ((minVal + crow[lane + 64]) - ui) - v1;
                if (!sc1 && r < spc1) { spc1 = r; p1 = i; }
            }
            {
                float r = ((minVal + crow[lane + 128]) - ui) - v2;
                if (!sc2 && r < spc2) { spc2 = r; p2 = i; }
            }
            const float m0 = sc0 ? NBIG : spc0;
            const float m1 = sc1 ? NBIG : spc1;
            const float m2 = sc2 ? NBIG : spc2;

            minVal = wave_min64(fminf(m0, fminf(m1, m2)));
            unsigned long long b0 = __ballot(m0 == minVal);
            unsigned long long b1 = __ballot(m1 == minVal);
            unsigned long long b2 = __ballot(m2 == minVal);
            int jstar;
            if (b0)      jstar = __ffsll(b0) - 1;
            else if (b1) jstar = 64 + __ffsll(b1) - 1;
            else         jstar = 128 + __ffsll(b2) - 1;

            sc0 |= (jstar == lane); sc1 |= (jstar == lane + 64); sc2 |= (jstar == lane + 128);
            const int rj = GET_I3(r, jstar);
            if (rj < 0) sink = jstar; else i = rj;
        }

        // dual updates
        u0 += (cur == lane) ? minVal : 0.f;
        u1 += (cur == lane + 64) ? minVal : 0.f;
        u2 += (cur == lane + 128) ? minVal : 0.f;
        spc_lds[lane] = spc0; spc_lds[lane + 64] = spc1; spc_lds[lane + 128] = spc2;
        if (sr0 && lane != cur)         u0 += minVal - spc_lds[c0];
        if (sr1 && (lane + 64) != cur)  u1 += minVal - spc_lds[c1];
        if (sr2 && (lane + 128) != cur) u2 += minVal - spc_lds[c2];
        if (sc0) v0 -= (minVal - spc0);
        if (sc1) v1 -= (minVal - spc1);
        if (sc2) v2 -= (minVal - spc2);

        // augment along stored path
        int j = sink;
        while (true) {
            const int pj = GET_I3(p, j);
            SET_I3(r, j, pj);
            const int nj = GET_I3(c, pj);
            SET_I3(c, pj, j);
            if (pj == cur) break;
            j = nj;
        }
    }

    // ---- CE partial: sum_r (lse[r] - pred[r][tgt[col4row[r]]]) ----
    float part = 0.f;
    {
        const int tc0 = tgt_lds[c0], tc1 = tgt_lds[c1], tc2 = tgt_lds[c2];
        part += lse_lds[lane]       - predb[(size_t)lane * CC + tc0];
        part += lse_lds[lane + 64]  - predb[(size_t)(lane + 64) * CC + tc1];
        part += lse_lds[lane + 128] - predb[(size_t)(lane + 128) * CC + tc2];
    }
    part = wave_sum64(part);
    if (lane == 0) ws_part[b] = part;
}

__launch_bounds__(64)
__global__ void reduce_kernel(const float* __restrict__ ws_part,
                              float* __restrict__ out) {
    int lane = threadIdx.x;
    float s = ws_part[lane] + ws_part[lane + 64];
    s = wave_sum64(s);
    if (lane == 0) out[0] = s / (float)(BB * QQ);
}

extern "C" void kernel_launch(void* const* d_in, const int* in_sizes, int n_in,
                              void* d_out, int out_size, void* d_ws, size_t ws_size,
                              hipStream_t stream) {
    const float* pred = (const float*)d_in[0];
    const int* targets = (const int*)d_in[1];
    float* out = (float*)d_out;
    float* ws = (float*)d_ws;

    const int lds_bytes = (QQ * QQ + 4 * QQ) * (int)sizeof(float);  // 150528 B

    hipLaunchKernelGGL(hungarian_kernel, dim3(BB), dim3(256), lds_bytes, stream,
                       pred, targets, ws);
    hipLaunchKernelGGL(reduce_kernel, dim3(1), dim3(64), 0, stream, ws, out);
}

// Round 5
// 836.934 us; speedup vs baseline: 2.1174x; 2.0615x over previous
//
#include <hip/hip_runtime.h>
#include <math.h>

// HungarianLoss: B=128 samples, each a 192x192 LSAP on
// cost[q][j] = -softmax(pred[q])[tgt[j]], then mean CE with matched classes.
//
// R5: back to the proven R2 structure (sequential JV shortest augmenting
// path from zero duals -- R3/R4 showed colmin-dual inits INCREASE total
// settles ~2x on this degenerate matrix). 4-wave fill (R4). New: per-step
// critical path trimmed via packed u32 (key|col) single-pass argmin-reduce
// (kills the ballot tail) and 4-DPP + 4-readlane + s_min finish.
// All solver state in registers, 3 rows/cols per lane.

#define BB 128
#define QQ 192
#define CC 512
#define NBIG 1e30f

template<int CTRL>
__device__ __forceinline__ int dpp_mov(int x) {
    return __builtin_amdgcn_update_dpp(x, x, CTRL, 0xf, 0xf, false);
}

__device__ __forceinline__ int readlane_i(int v, int l) {
    return __builtin_amdgcn_readlane(v, l);
}
__device__ __forceinline__ float readlane_f(float v, int l) {
    return __int_as_float(__builtin_amdgcn_readlane(__float_as_int(v), l));
}
__device__ __forceinline__ unsigned umin_(unsigned a, unsigned b) { return a < b ? a : b; }

// full 64-lane reduces for the fill phase (validated R1-R4)
__device__ __forceinline__ float wave_max64(float x) {
    x = fmaxf(x, __int_as_float(dpp_mov<0x111>(__float_as_int(x))));
    x = fmaxf(x, __int_as_float(dpp_mov<0x112>(__float_as_int(x))));
    x = fmaxf(x, __int_as_float(dpp_mov<0x114>(__float_as_int(x))));
    x = fmaxf(x, __int_as_float(dpp_mov<0x118>(__float_as_int(x))));
    x = fmaxf(x, __int_as_float(dpp_mov<0x142>(__float_as_int(x))));
    x = fmaxf(x, __int_as_float(dpp_mov<0x143>(__float_as_int(x))));
    return __int_as_float(__builtin_amdgcn_readlane(__float_as_int(x), 63));
}
__device__ __forceinline__ float wave_sum64(float x) {
    x += __int_as_float(dpp_mov<0x111>(__float_as_int(x)));
    x += __int_as_float(dpp_mov<0x112>(__float_as_int(x)));
    x += __int_as_float(dpp_mov<0x114>(__float_as_int(x)));
    x += __int_as_float(dpp_mov<0x118>(__float_as_int(x)));
    x += __int_as_float(dpp_mov<0x142>(__float_as_int(x)));
    x += __int_as_float(dpp_mov<0x143>(__float_as_int(x)));
    return __int_as_float(__builtin_amdgcn_readlane(__float_as_int(x), 63));
}

// packed-key min over 64 lanes: 4 DPP row_shr levels (16-lane rows) then
// 4 readlanes + scalar mins (cheaper than 2 row_bcast DPP levels).
__device__ __forceinline__ unsigned wave_min_pk(unsigned x) {
    x = umin_(x, (unsigned)dpp_mov<0x111>((int)x));
    x = umin_(x, (unsigned)dpp_mov<0x112>((int)x));
    x = umin_(x, (unsigned)dpp_mov<0x114>((int)x));
    x = umin_(x, (unsigned)dpp_mov<0x118>((int)x));
    unsigned a = (unsigned)readlane_i((int)x, 15);
    unsigned b = (unsigned)readlane_i((int)x, 31);
    unsigned c = (unsigned)readlane_i((int)x, 47);
    unsigned d = (unsigned)readlane_i((int)x, 63);
    return umin_(umin_(a, b), umin_(c, d));
}

// sign-aware monotonic float->u32 key (handles tiny negative reduced costs)
__device__ __forceinline__ unsigned fkey(float f) {
    unsigned b = __float_as_uint(f);
    return b ^ (((unsigned)((int)b >> 31)) | 0x80000000u);
}

// distributed-register accessors (idx -> owner lane idx&63, slot idx>>6)
#define GET_I3(a, idx) readlane_i((((idx)>>6)==0) ? a##0 : ((((idx)>>6)==1) ? a##1 : a##2), (idx)&63)
#define GET_F3(a, idx) readlane_f((((idx)>>6)==0) ? a##0 : ((((idx)>>6)==1) ? a##1 : a##2), (idx)&63)
#define SET_I3(a, idx, val) do { const int _s=(idx)>>6, _l=(idx)&63; \
    if (_s==0) { if (lane==_l) a##0=(val); } \
    else if (_s==1) { if (lane==_l) a##1=(val); } \
    else { if (lane==_l) a##2=(val); } } while(0)

__launch_bounds__(256)
__global__ void hungarian_kernel(const float* __restrict__ pred,
                                 const int* __restrict__ targets,
                                 float* __restrict__ ws_part) {
    const int b = blockIdx.x;
    const int lane = threadIdx.x & 63;
    const int wv = threadIdx.x >> 6;

    extern __shared__ float smem[];
    float* cost    = smem;                   // [QQ*QQ] read-only after fill
    float* spc_lds = cost + QQ * QQ;         // [QQ] per-solve spc dump
    float* lse_lds = spc_lds + QQ;           // [QQ]
    int*   tgt_lds = (int*)(lse_lds + QQ);   // [QQ]

    // ---- targets ----
    const int t0 = targets[b * QQ + lane];
    const int t1 = targets[b * QQ + lane + 64];
    const int t2 = targets[b * QQ + lane + 128];
    if (wv == 0) { tgt_lds[lane] = t0; tgt_lds[lane + 64] = t1; tgt_lds[lane + 128] = t2; }

    // ---- fill: 4 waves, 48 rows each (validated R4) ----
    const float* predb = pred + (size_t)b * QQ * CC;
    {
        const int q0 = wv * 48, q1 = q0 + 48;
        float x[8];
        #pragma unroll
        for (int k = 0; k < 8; k++) x[k] = predb[(size_t)q0 * CC + lane + 64 * k];
        for (int q = q0; q < q1; q++) {
            const float* row = predb + (size_t)q * CC;
            float g0 = row[t0], g1 = row[t1], g2 = row[t2];
            float xn[8];
            if (q + 1 < q1) {
                const float* nrow = row + CC;
                #pragma unroll
                for (int k = 0; k < 8; k++) xn[k] = nrow[lane + 64 * k];
            }
            float mx = x[0];
            #pragma unroll
            for (int k = 1; k < 8; k++) mx = fmaxf(mx, x[k]);
            mx = wave_max64(mx);
            float s = 0.f;
            #pragma unroll
            for (int k = 0; k < 8; k++) s += expf(x[k] - mx);
            s = wave_sum64(s);
            float lse = mx + logf(s);
            if (lane == 0) lse_lds[q] = lse;
            cost[q * QQ + lane]       = -expf(g0 - lse);
            cost[q * QQ + lane + 64]  = -expf(g1 - lse);
            cost[q * QQ + lane + 128] = -expf(g2 - lse);
            #pragma unroll
            for (int k = 0; k < 8; k++) x[k] = xn[k];
        }
    }
    __syncthreads();
    if (wv != 0) return;
    // single wave from here: in-wave LDS ordering via waitcnt, no barriers.

    // ---- solver state: 3 rows + 3 cols per lane ----
    float u0 = 0.f, u1 = 0.f, u2 = 0.f;   // row duals
    float v0 = 0.f, v1 = 0.f, v2 = 0.f;   // col duals
    int   c0 = -1, c1 = -1, c2 = -1;      // col4row
    int   r0 = -1, r1 = -1, r2 = -1;      // row4col

    // ---- sequential JV shortest augmenting path (R2 semantics) ----
    for (int cur = 0; cur < QQ; cur++) {
        float spc0 = NBIG, spc1 = NBIG, spc2 = NBIG;
        int   p0 = 0, p1 = 0, p2 = 0;
        int   sc0 = 0, sc1 = 0, sc2 = 0;
        unsigned long long SRm0 = 0, SRm1 = 0, SRm2 = 0;  // scanned-row masks (scalar)
        int   i = cur;
        float minVal = 0.f;
        int   sink;

        while (true) {
            {   // SR[i] = 1 (scalar mask ops, off VALU critical path)
                const int is = i >> 6, il = i & 63;
                if (is == 0)      SRm0 |= 1ull << il;
                else if (is == 1) SRm1 |= 1ull << il;
                else              SRm2 |= 1ull << il;
            }
            const float* crow = cost + i * QQ;
            const float cA = crow[lane];
            const float cB = crow[lane + 64];
            const float cD = crow[lane + 128];
            const float ui = GET_F3(u, i);   // overlaps the ds_read latency

            // relax (reference ordering + settled guard semantics)
            float rA = ((minVal + cA) - ui) - v0;  rA = sc0 ? NBIG : rA;
            if (rA < spc0) { spc0 = rA; p0 = i; }
            float rB = ((minVal + cB) - ui) - v1;  rB = sc1 ? NBIG : rB;
            if (rB < spc1) { spc1 = rB; p1 = i; }
            float rD = ((minVal + cD) - ui) - v2;  rD = sc2 ? NBIG : rD;
            if (rD < spc2) { spc2 = rD; p2 = i; }

            // packed (key|col) argmin: one u32 reduce gives min AND argmin;
            // exact ties (duplicate columns) break to lowest col like jnp.argmin
            unsigned pkA = sc0 ? 0xFFFFFFFFu : ((fkey(spc0) & 0xFFFFFF00u) | (unsigned)lane);
            unsigned pkB = sc1 ? 0xFFFFFFFFu : ((fkey(spc1) & 0xFFFFFF00u) | (unsigned)(lane + 64));
            unsigned pkD = sc2 ? 0xFFFFFFFFu : ((fkey(spc2) & 0xFFFFFF00u) | (unsigned)(lane + 128));
            const unsigned pk = wave_min_pk(umin_(umin_(pkA, pkB), pkD));
            const int jstar = (int)(pk & 255u);
            const int os = jstar >> 6, ol = jstar & 63;

            // exact minVal from the winner's spc (parallel to next-row chain)
            minVal = readlane_f(os == 0 ? spc0 : (os == 1 ? spc1 : spc2), ol);
            sc0 |= (jstar == lane);
            sc1 |= (jstar == lane + 64);
            sc2 |= (jstar == lane + 128);
            const int rj = readlane_i(os == 0 ? r0 : (os == 1 ? r1 : r2), ol);
            if (rj < 0) { sink = jstar; break; }
            i = rj;
        }

        // ---- dual updates ----
        u0 += (cur == lane) ? minVal : 0.f;
        u1 += (cur == lane + 64) ? minVal : 0.f;
        u2 += (cur == lane + 128) ? minVal : 0.f;
        spc_lds[lane] = spc0; spc_lds[lane + 64] = spc1; spc_lds[lane + 128] = spc2;
        const int f0 = (int)((SRm0 >> lane) & 1ull);
        const int f1 = (int)((SRm1 >> lane) & 1ull);
        const int f2 = (int)((SRm2 >> lane) & 1ull);
        if (f0 && lane != cur)         u0 += minVal - spc_lds[c0];
        if (f1 && (lane + 64) != cur)  u1 += minVal - spc_lds[c1];
        if (f2 && (lane + 128) != cur) u2 += minVal - spc_lds[c2];
        if (sc0) v0 -= (minVal - spc0);
        if (sc1) v1 -= (minVal - spc1);
        if (sc2) v2 -= (minVal - spc2);

        // ---- augment along stored path ----
        int j = sink;
        while (true) {
            const int pj = GET_I3(p, j);
            SET_I3(r, j, pj);
            const int nj = GET_I3(c, pj);
            SET_I3(c, pj, j);
            if (pj == cur) break;
            j = nj;
        }
    }

    // ---- CE partial: sum_r (lse[r] - pred[r][tgt[col4row[r]]]) ----
    float part = 0.f;
    {
        const int tc0 = tgt_lds[c0], tc1 = tgt_lds[c1], tc2 = tgt_lds[c2];
        part += lse_lds[lane]       - predb[(size_t)lane * CC + tc0];
        part += lse_lds[lane + 64]  - predb[(size_t)(lane + 64) * CC + tc1];
        part += lse_lds[lane + 128] - predb[(size_t)(lane + 128) * CC + tc2];
    }
    part = wave_sum64(part);
    if (lane == 0) ws_part[b] = part;
}

__launch_bounds__(64)
__global__ void reduce_kernel(const float* __restrict__ ws_part,
                              float* __restrict__ out) {
    int lane = threadIdx.x;
    float s = ws_part[lane] + ws_part[lane + 64];
    s = wave_sum64(s);
    if (lane == 0) out[0] = s / (float)(BB * QQ);
}

extern "C" void kernel_launch(void* const* d_in, const int* in_sizes, int n_in,
                              void* d_out, int out_size, void* d_ws, size_t ws_size,
                              hipStream_t stream) {
    const float* pred = (const float*)d_in[0];
    const int* targets = (const int*)d_in[1];
    float* out = (float*)d_out;
    float* ws = (float*)d_ws;

    const int lds_bytes = (QQ * QQ + 3 * QQ) * (int)sizeof(float);  // 149760 B

    hipLaunchKernelGGL(hungarian_kernel, dim3(BB), dim3(256), lds_bytes, stream,
                       pred, targets, ws);
    hipLaunchKernelGGL(reduce_kernel, dim3(1), dim3(64), 0, stream, ws, out);
}